// Round 8
// baseline (443.870 us; speedup 1.0000x reference)
//
#include <hip/hip_runtime.h>
#include <hip/hip_bf16.h>
#include <cstdint>

#define NEGV (-10000.0f)

typedef short bf16x8 __attribute__((ext_vector_type(8)));
typedef short bf16x4 __attribute__((ext_vector_type(4)));
typedef float f32x4 __attribute__((ext_vector_type(4)));

__device__ __forceinline__ short f2bf(float f) {
  union { float f; uint32_t u; } v; v.f = f;
  uint32_t u = v.u + 0x7fffu + ((v.u >> 16) & 1u);
  return (short)(u >> 16);
}
__device__ __forceinline__ float b2f(short s) {
  union { uint32_t u; float f; } v; v.u = ((uint32_t)(uint16_t)s) << 16;
  return v.f;
}
__device__ __forceinline__ uint32_t pk2(float lo, float hi) {
  union { __hip_bfloat162 h2; uint32_t u; } cv;
  cv.h2.x = __float2bfloat16(lo);
  cv.h2.y = __float2bfloat16(hi);
  return cv.u;
}

// ---------------- P1: weight combine + bf16 casts ----------------
__global__ void prep_weights(const float* __restrict__ W1, const float* __restrict__ W2,
                             short* __restrict__ Wk, short* __restrict__ Wd,
                             short* __restrict__ W2b) {
  int idx = blockIdx.x * 256 + threadIdx.x;
  if (idx < 32768) {
    int h = idx >> 7, d = idx & 127;
    Wk[idx] = f2bf(W1[h * 512 + 128 + d] - W1[h * 512 + 256 + d]);
  } else if (idx < 65536) {
    int i = idx - 32768;
    int h = i >> 7, d = i & 127;
    Wd[i] = f2bf(W1[h * 512 + 384 + d]);
  } else {
    int i = idx - 65536;
    W2b[i] = f2bf(W2[i]);
  }
}

// ---------------- P2: U[b][h] = b1[h] + sum_d (W1[h][d]+W1[h][256+d]) * q[b][d] ----
__global__ void prep_u(const float* __restrict__ query, const float* __restrict__ W1,
                       const float* __restrict__ b1, float* __restrict__ U) {
  __shared__ float q8[8][128];
  int tid = threadIdx.x;
  int b0 = blockIdx.x * 8;
  for (int i = tid; i < 1024; i += 256)
    q8[i >> 7][i & 127] = query[(size_t)(b0 + (i >> 7)) * 128 + (i & 127)];
  __syncthreads();
  int h = tid;
  const float4* w0 = (const float4*)(W1 + (size_t)h * 512);
  const float4* w1 = (const float4*)(W1 + (size_t)h * 512 + 256);
  float acc[8];
  float bb = b1[h];
#pragma unroll
  for (int i = 0; i < 8; ++i) acc[i] = bb;
  for (int d4 = 0; d4 < 32; ++d4) {
    float4 wa = w0[d4], wb = w1[d4];
    float wv0 = wa.x + wb.x, wv1 = wa.y + wb.y, wv2 = wa.z + wb.z, wv3 = wa.w + wb.w;
#pragma unroll
    for (int i = 0; i < 8; ++i) {
      float4 qv = ((const float4*)q8[i])[d4];
      acc[i] += wv0 * qv.x + wv1 * qv.y + wv2 * qv.z + wv3 * qv.w;
    }
  }
#pragma unroll
  for (int i = 0; i < 8; ++i) U[(size_t)(b0 + i) * 256 + h] = acc[i];
}

// ---------------- K2: scores. Block = b, 4 waves, streaming 16-row tiles ----------
// R8: lb(256,4) targeting 4 blocks/CU; prefetch distance 2 (st_new->st_hold),
// 1 barrier/tile.
__global__ __launch_bounds__(256, 4) void din_scores(
    const float* __restrict__ query, const float* __restrict__ keys,
    const float* __restrict__ b2p, const float* __restrict__ a1p,
    const float* __restrict__ a2p, const float* __restrict__ W3,
    const float* __restrict__ U, const short* __restrict__ Wk,
    const short* __restrict__ Wd, const short* __restrict__ W2b,
    float* __restrict__ scores_g) {
  __shared__ short Kt[2][16 * 128];   // 8 KB: streaming key tiles, XOR-swizzled
  __shared__ short H1[2][16 * 256];   // 16 KB: per-tile h1, XOR-swizzled
  __shared__ float wred[4][208];      // 3.3 KB: per-wave score partials
  __shared__ float Ul[256];
  __shared__ float b2l[128];
  __shared__ float w3l[128];

  const int tid = threadIdx.x;
  const int b = blockIdx.x;
  const int lane = tid & 63, wid = tid >> 6;  // 4 waves
  const int lr = lane & 15, lg = lane >> 4;

  const float a1 = a1p[0], a2 = a2p[0];

  Ul[tid] = U[(size_t)b * 256 + tid];
  if (tid < 128) { b2l[tid] = b2p[tid]; w3l[tid] = W3[tid]; }

  // ---- persistent fragments ----
  // GEMM1 A: M_b[h][d] = Wk + Wd.*q ; wave owns 64 h (nt=0..3)
  bf16x8 mf[4][4];
  {
    const float* qrow = query + (size_t)b * 128;
#pragma unroll
    for (int nt = 0; nt < 4; ++nt) {
      int h = wid * 64 + nt * 16 + lr;
#pragma unroll
      for (int ks = 0; ks < 4; ++ks) {
        int d0 = ks * 32 + lg * 8;
        bf16x8 wk = *(const bf16x8*)(Wk + h * 128 + d0);
        bf16x8 wd = *(const bf16x8*)(Wd + h * 128 + d0);
        float4 q0 = *(const float4*)(qrow + d0);
        float4 q1 = *(const float4*)(qrow + d0 + 4);
        float qv[8] = {q0.x, q0.y, q0.z, q0.w, q1.x, q1.y, q1.z, q1.w};
        float mv[8];
#pragma unroll
        for (int j = 0; j < 8; ++j) mv[j] = b2f(wk[j]) + b2f(wd[j]) * qv[j];
        union { bf16x8 v; uint32_t u[4]; } mm;
#pragma unroll
        for (int j = 0; j < 4; ++j) mm.u[j] = pk2(mv[2 * j], mv[2 * j + 1]);
        mf[nt][ks] = mm.v;
      }
    }
  }
  // GEMM2 A: W2[g][h]; wave owns 32 g (nt2=0..1)
  bf16x8 w2f[2][8];
#pragma unroll
  for (int nt2 = 0; nt2 < 2; ++nt2) {
    int g = wid * 32 + nt2 * 16 + lr;
#pragma unroll
    for (int ks = 0; ks < 8; ++ks)
      w2f[nt2][ks] = *(const bf16x8*)(W2b + g * 256 + ks * 32 + lg * 8);
  }

  // staging geometry: 16 threads/row, 8 floats (32B) per thread
  const int srow = tid >> 4;          // 0..15
  const int scol = (tid & 15) * 8;    // 0..120
  const int ssw = (srow & 7) << 3;

  float4 h0a, h0b;  // st_hold: regs for tile t+1
  // prologue: stage tile 0 directly; issue tile-1 loads into st_hold
  {
    const float4* kp4 = (const float4*)(keys + ((size_t)b * 200 + srow) * 128 + scol);
    float4 s0 = kp4[0], s1 = kp4[1];
    union { bf16x8 v; uint32_t u[4]; } w;
    w.u[0] = pk2(s0.x, s0.y); w.u[1] = pk2(s0.z, s0.w);
    w.u[2] = pk2(s1.x, s1.y); w.u[3] = pk2(s1.z, s1.w);
    *(bf16x8*)(&Kt[0][srow * 128 + (scol ^ ssw)]) = w.v;
    const float4* kp4b = (const float4*)(keys + ((size_t)b * 200 + 16 + srow) * 128 + scol);
    h0a = kp4b[0]; h0b = kp4b[1];
  }
  __syncthreads();

  // ---- 13 tiles of 16 l (tile 12: rows 192..199 + 8 zero rows) ----
  for (int t = 0; t < 13; ++t) {
    const int buf = t & 1;

    // issue loads for tile t+2 (consumed at t+1's LDS write -> ~1.2 tiles in flight)
    float4 n0, n1;
    if (t < 11) {
      int gl = (t + 2) * 16 + srow;
      n0 = n1 = make_float4(0.f, 0.f, 0.f, 0.f);
      if (gl < 200) {
        const float4* kp4 = (const float4*)(keys + ((size_t)b * 200 + gl) * 128 + scol);
        n0 = kp4[0]; n1 = kp4[1];
      }
    }

    // GEMM1: D[h][l] = M_b · K^T
    const int sw = (lr & 7) << 3;
    bf16x8 kf[4];
#pragma unroll
    for (int ks = 0; ks < 4; ++ks)
      kf[ks] = *(const bf16x8*)(&Kt[buf][lr * 128 + ((ks * 32 + lg * 8) ^ sw)]);
    f32x4 acc[4];
#pragma unroll
    for (int nt = 0; nt < 4; ++nt)
#pragma unroll
      for (int r = 0; r < 4; ++r) acc[nt][r] = Ul[wid * 64 + nt * 16 + lg * 4 + r];
    __builtin_amdgcn_s_setprio(1);
#pragma unroll
    for (int ks = 0; ks < 4; ++ks)
#pragma unroll
      for (int nt = 0; nt < 4; ++nt)
        acc[nt] = __builtin_amdgcn_mfma_f32_16x16x32_bf16(mf[nt][ks], kf[ks], acc[nt], 0, 0, 0);
    __builtin_amdgcn_s_setprio(0);
    // PReLU(a1) -> H1[buf][lr][h], packed 8B writes
    short* h1b = H1[buf];
#pragma unroll
    for (int nt = 0; nt < 4; ++nt) {
      float v0 = acc[nt][0], v1 = acc[nt][1], v2 = acc[nt][2], v3 = acc[nt][3];
      v0 = (v0 >= 0.f) ? v0 : a1 * v0;
      v1 = (v1 >= 0.f) ? v1 : a1 * v1;
      v2 = (v2 >= 0.f) ? v2 : a1 * v2;
      v3 = (v3 >= 0.f) ? v3 : a1 * v3;
      union { bf16x4 v; uint32_t u[2]; } hh;
      hh.u[0] = pk2(v0, v1); hh.u[1] = pk2(v2, v3);
      int h0 = wid * 64 + nt * 16 + lg * 4;
      *(bf16x4*)(&h1b[lr * 256 + (h0 ^ sw)]) = hh.v;
    }

    // write tile t+1's keys (held in regs since tile t-1) into the other buffer
    if (t < 12) {
      union { bf16x8 v; uint32_t u[4]; } w;
      w.u[0] = pk2(h0a.x, h0a.y); w.u[1] = pk2(h0a.z, h0a.w);
      w.u[2] = pk2(h0b.x, h0b.y); w.u[3] = pk2(h0b.z, h0b.w);
      *(bf16x8*)(&Kt[buf ^ 1][srow * 128 + (scol ^ ssw)]) = w.v;
    }
    __syncthreads();  // the ONLY barrier per tile

    // GEMM2: D[g][l] = W2 · H1^T, K=256
    f32x4 acc2[2];
#pragma unroll
    for (int nt2 = 0; nt2 < 2; ++nt2)
#pragma unroll
      for (int r = 0; r < 4; ++r) acc2[nt2][r] = b2l[wid * 32 + nt2 * 16 + lg * 4 + r];
    __builtin_amdgcn_s_setprio(1);
#pragma unroll
    for (int ks = 0; ks < 8; ++ks) {
      bf16x8 hf = *(const bf16x8*)(&h1b[lr * 256 + ((ks * 32 + lg * 8) ^ sw)]);
      acc2[0] = __builtin_amdgcn_mfma_f32_16x16x32_bf16(w2f[0][ks], hf, acc2[0], 0, 0, 0);
      acc2[1] = __builtin_amdgcn_mfma_f32_16x16x32_bf16(w2f[1][ks], hf, acc2[1], 0, 0, 0);
    }
    __builtin_amdgcn_s_setprio(0);
    float s = 0.f;
#pragma unroll
    for (int nt2 = 0; nt2 < 2; ++nt2)
#pragma unroll
      for (int r = 0; r < 4; ++r) {
        float v = acc2[nt2][r];
        v = (v >= 0.f) ? v : a2 * v;
        s += v * w3l[wid * 32 + nt2 * 16 + lg * 4 + r];
      }
    s += __shfl_xor(s, 16);
    s += __shfl_xor(s, 32);
    if (lg == 0) wred[wid][t * 16 + lr] = s;

    // rotate prefetch regs
    if (t < 11) { h0a = n0; h0b = n1; }
    // no barrier here: tile t+1 writes only the other Kt/H1 buffers
  }
  __syncthreads();

  if (tid < 200) {
    float s = wred[0][tid] + wred[1][tid] + wred[2][tid] + wred[3][tid];
    scores_g[(size_t)b * 200 + tid] = s;
  }
}

// ---------------- K3: masked softmax + weighted sum (streaming) ----------------
__global__ __launch_bounds__(256) void din_wsum(
    const float* __restrict__ keys, const int* __restrict__ mask,
    const float* __restrict__ scores_g, float* __restrict__ out) {
  __shared__ float wl[208];
  __shared__ float red[8];
  __shared__ float opart[8][128];

  const int tid = threadIdx.x;
  const int b = blockIdx.x;
  const int lane = tid & 63, wid = tid >> 6;  // 4 waves

  float val = NEGV;
  int mk = 0;
  if (tid < 200) {
    mk = mask[(size_t)b * 200 + tid];
    val = mk ? scores_g[(size_t)b * 200 + tid] : NEGV;
  }
  float m = val;
#pragma unroll
  for (int off = 1; off < 64; off <<= 1) m = fmaxf(m, __shfl_xor(m, off));
  if (lane == 0) red[wid] = m;
  __syncthreads();
  float smax = fmaxf(fmaxf(red[0], red[1]), fmaxf(red[2], red[3]));
  float pex = (tid < 200 && mk) ? __expf(val - smax) : 0.f;
  float s = pex;
#pragma unroll
  for (int off = 1; off < 64; off <<= 1) s += __shfl_xor(s, off);
  if (lane == 0) red[4 + wid] = s;
  __syncthreads();
  float ssum = red[4] + red[5] + red[6] + red[7];
  float winv = (ssum > 0.f) ? 1.f / ssum : 0.f;
  if (tid < 208) wl[tid] = (tid < 200) ? pex * winv : 0.f;
  __syncthreads();

  {
    const int d4 = (tid & 31) << 2;  // 0..124
    const int slice = tid >> 5;      // 0..7
    float ax = 0.f, ay = 0.f, az = 0.f, aw = 0.f;
    for (int l = slice; l < 200; l += 8) {
      float wv = wl[l];
      float4 kv = *(const float4*)(keys + ((size_t)b * 200 + l) * 128 + d4);
      ax += wv * kv.x; ay += wv * kv.y; az += wv * kv.z; aw += wv * kv.w;
    }
    *(float4*)(&opart[slice][d4]) = make_float4(ax, ay, az, aw);
  }
  __syncthreads();
  if (tid < 128) {
    float acc = 0.f;
#pragma unroll
    for (int i = 0; i < 8; ++i) acc += opart[i][tid];
    out[(size_t)b * 128 + tid] = acc;
  }
}

extern "C" void kernel_launch(void* const* d_in, const int* in_sizes, int n_in,
                              void* d_out, int out_size, void* d_ws, size_t ws_size,
                              hipStream_t stream) {
  const float* query = (const float*)d_in[0];
  const float* keys  = (const float*)d_in[1];
  const int*   maskp = (const int*)d_in[2];
  const float* W1    = (const float*)d_in[3];
  const float* b1    = (const float*)d_in[4];
  const float* a1    = (const float*)d_in[5];
  const float* W2    = (const float*)d_in[6];
  const float* b2    = (const float*)d_in[7];
  const float* a2    = (const float*)d_in[8];
  const float* W3    = (const float*)d_in[9];
  float* out = (float*)d_out;

  // workspace layout
  float* U        = (float*)d_ws;                        // 2 MiB
  short* Wk       = (short*)((char*)d_ws + 2097152);     // 64 KiB
  short* Wd       = Wk + 32768;                          // 64 KiB
  short* W2b      = Wd + 32768;                          // 64 KiB
  float* scores_g = (float*)((char*)d_ws + 2097152 + 196608);  // 1.6 MiB

  prep_weights<<<384, 256, 0, stream>>>(W1, W2, Wk, Wd, W2b);
  prep_u<<<256, 256, 0, stream>>>(query, W1, b1, U);
  din_scores<<<2048, 256, 0, stream>>>(query, keys, b2, a1, a2, W3,
                                       U, Wk, Wd, W2b, scores_g);
  din_wsum<<<2048, 256, 0, stream>>>(keys, maskp, scores_g, out);
}

// Round 9
// 188.286 us; speedup vs baseline: 2.3574x; 2.3574x over previous
//
#include <hip/hip_runtime.h>
#include <hip/hip_bf16.h>
#include <cstdint>

#define NEGV (-10000.0f)

typedef short bf16x8 __attribute__((ext_vector_type(8)));
typedef short bf16x4 __attribute__((ext_vector_type(4)));
typedef float f32x4 __attribute__((ext_vector_type(4)));

__device__ __forceinline__ short f2bf(float f) {
  union { float f; uint32_t u; } v; v.f = f;
  uint32_t u = v.u + 0x7fffu + ((v.u >> 16) & 1u);
  return (short)(u >> 16);
}
__device__ __forceinline__ float b2f(short s) {
  union { uint32_t u; float f; } v; v.u = ((uint32_t)(uint16_t)s) << 16;
  return v.f;
}
__device__ __forceinline__ uint32_t pk2(float lo, float hi) {
  union { __hip_bfloat162 h2; uint32_t u; } cv;
  cv.h2.x = __float2bfloat16(lo);
  cv.h2.y = __float2bfloat16(hi);
  return cv.u;
}

// ---------------- P1: weight combine + bf16 casts ----------------
__global__ void prep_weights(const float* __restrict__ W1, const float* __restrict__ W2,
                             short* __restrict__ Wk, short* __restrict__ Wd,
                             short* __restrict__ W2b) {
  int idx = blockIdx.x * 256 + threadIdx.x;
  if (idx < 32768) {
    int h = idx >> 7, d = idx & 127;
    Wk[idx] = f2bf(W1[h * 512 + 128 + d] - W1[h * 512 + 256 + d]);
  } else if (idx < 65536) {
    int i = idx - 32768;
    int h = i >> 7, d = i & 127;
    Wd[i] = f2bf(W1[h * 512 + 384 + d]);
  } else {
    int i = idx - 65536;
    W2b[i] = f2bf(W2[i]);
  }
}

// ---------------- P2: U[b][h] = b1[h] + sum_d (W1[h][d]+W1[h][256+d]) * q[b][d] ----
__global__ void prep_u(const float* __restrict__ query, const float* __restrict__ W1,
                       const float* __restrict__ b1, float* __restrict__ U) {
  __shared__ float q8[8][128];
  int tid = threadIdx.x;
  int b0 = blockIdx.x * 8;
  for (int i = tid; i < 1024; i += 256)
    q8[i >> 7][i & 127] = query[(size_t)(b0 + (i >> 7)) * 128 + (i & 127)];
  __syncthreads();
  int h = tid;
  const float4* w0 = (const float4*)(W1 + (size_t)h * 512);
  const float4* w1 = (const float4*)(W1 + (size_t)h * 512 + 256);
  float acc[8];
  float bb = b1[h];
#pragma unroll
  for (int i = 0; i < 8; ++i) acc[i] = bb;
  for (int d4 = 0; d4 < 32; ++d4) {
    float4 wa = w0[d4], wb = w1[d4];
    float wv0 = wa.x + wb.x, wv1 = wa.y + wb.y, wv2 = wa.z + wb.z, wv3 = wa.w + wb.w;
#pragma unroll
    for (int i = 0; i < 8; ++i) {
      float4 qv = ((const float4*)q8[i])[d4];
      acc[i] += wv0 * qv.x + wv1 * qv.y + wv2 * qv.z + wv3 * qv.w;
    }
  }
#pragma unroll
  for (int i = 0; i < 8; ++i) U[(size_t)(b0 + i) * 256 + h] = acc[i];
}

// ---------------- K2: scores. One 1024-thr block per b, wave-specialized. --------
// Waves 0-7: GEMM1 (h=32 each, mf 32 VGPR). Waves 8-15: GEMM2 (g=16 each,
// w2f 32 VGPR) + key staging (T14 split). Producer-consumer on dbuf H1/Kt,
// 1 barrier/phase, 14 phases. No launch-bounds 2nd arg: empirically 1 block/CU
// resident -> 16 waves/CU (2x R7).
__global__ __launch_bounds__(1024) void din_scores(
    const float* __restrict__ query, const float* __restrict__ keys,
    const float* __restrict__ b2p, const float* __restrict__ a1p,
    const float* __restrict__ a2p, const float* __restrict__ W3,
    const float* __restrict__ U, const short* __restrict__ Wk,
    const short* __restrict__ Wd, const short* __restrict__ W2b,
    float* __restrict__ scores_g) {
  __shared__ short Kt[2][16 * 128];   // 8 KB: bf16 key tiles, XOR-swizzled
  __shared__ short H1[2][16 * 256];   // 16 KB: h1 tiles [l][h], XOR-swizzled
  __shared__ float wred[8][208];      // 6.5 KB: per-G2-wave score partials

  const int tid = threadIdx.x;
  const int b = blockIdx.x;
  const int lane = tid & 63, wid = tid >> 6;  // 16 waves
  const int lr = lane & 15, lg = lane >> 4;
  const bool isG1 = wid < 8;

  // shared fragment storage: G1 uses frag[nt*4+ks] as mf; G2 uses frag[ks] as w2f
  bf16x8 frag[8];
  f32x4 accA, accB;           // G1: two h-tiles; G2: accA only
  float uv0[4], uv1[4];       // G1: U preload  | G2: b2v in uv0, w3v in uv1
  float alpha;                // G1: a1 | G2: a2

  if (isG1) {
    alpha = a1p[0];
    const float* qrow = query + (size_t)b * 128;
#pragma unroll
    for (int nt = 0; nt < 2; ++nt) {
      int h = wid * 32 + nt * 16 + lr;
#pragma unroll
      for (int ks = 0; ks < 4; ++ks) {
        int d0 = ks * 32 + lg * 8;
        bf16x8 wk = *(const bf16x8*)(Wk + h * 128 + d0);
        bf16x8 wd = *(const bf16x8*)(Wd + h * 128 + d0);
        float4 q0 = *(const float4*)(qrow + d0);
        float4 q1 = *(const float4*)(qrow + d0 + 4);
        float qv[8] = {q0.x, q0.y, q0.z, q0.w, q1.x, q1.y, q1.z, q1.w};
        float mv[8];
#pragma unroll
        for (int j = 0; j < 8; ++j) mv[j] = b2f(wk[j]) + b2f(wd[j]) * qv[j];
        union { bf16x8 v; uint32_t u[4]; } mm;
#pragma unroll
        for (int j = 0; j < 4; ++j) mm.u[j] = pk2(mv[2 * j], mv[2 * j + 1]);
        frag[nt * 4 + ks] = mm.v;
      }
    }
#pragma unroll
    for (int r = 0; r < 4; ++r) {
      uv0[r] = U[(size_t)b * 256 + wid * 32 + lg * 4 + r];
      uv1[r] = U[(size_t)b * 256 + wid * 32 + 16 + lg * 4 + r];
    }
  } else {
    alpha = a2p[0];
    int g = (wid - 8) * 16 + lr;
#pragma unroll
    for (int ks = 0; ks < 8; ++ks)
      frag[ks] = *(const bf16x8*)(W2b + g * 256 + ks * 32 + lg * 8);
#pragma unroll
    for (int r = 0; r < 4; ++r) {
      int gg = (wid - 8) * 16 + lg * 4 + r;
      uv0[r] = b2p[gg];
      uv1[r] = W3[gg];
    }
  }

  // staging geometry (G2 waves, 512 threads): 4 floats each
  const int j = tid - 512;            // 0..511 on G2
  const int srow = j >> 5;            // 0..15
  const int scol = (j & 31) * 4;      // float/short col, 0..124
  const int ssw = (srow & 7) << 3;

  // prologue: G2 stages tile 0
  if (!isG1) {
    float4 st = *(const float4*)(keys + ((size_t)b * 200 + srow) * 128 + scol);
    union { bf16x4 v; uint32_t u[2]; } w;
    w.u[0] = pk2(st.x, st.y); w.u[1] = pk2(st.z, st.w);
    *(bf16x4*)(&Kt[0][srow * 128 + (scol ^ ssw)]) = w.v;
  }
  __syncthreads();

  const int sw = (lr & 7) << 3;

  // ---- 14 phases: G1 does tile ph (ph<13), G2 does tile ph-1 (ph>=1) ----
  for (int ph = 0; ph < 14; ++ph) {
    const int buf = ph & 1;

    float4 st;
    bool sv = false;
    if (!isG1 && ph < 12) {           // stage tile ph+1 into Kt[buf^1]
      int gl = (ph + 1) * 16 + srow;
      st = make_float4(0.f, 0.f, 0.f, 0.f);
      sv = true;
      if (gl < 200) st = *(const float4*)(keys + ((size_t)b * 200 + gl) * 128 + scol);
    }

    if (isG1) {
      if (ph < 13) {
        bf16x8 kf[4];
#pragma unroll
        for (int ks = 0; ks < 4; ++ks)
          kf[ks] = *(const bf16x8*)(&Kt[buf][lr * 128 + ((ks * 32 + lg * 8) ^ sw)]);
#pragma unroll
        for (int r = 0; r < 4; ++r) { accA[r] = uv0[r]; accB[r] = uv1[r]; }
        __builtin_amdgcn_s_setprio(1);
#pragma unroll
        for (int ks = 0; ks < 4; ++ks) {
          accA = __builtin_amdgcn_mfma_f32_16x16x32_bf16(frag[ks], kf[ks], accA, 0, 0, 0);
          accB = __builtin_amdgcn_mfma_f32_16x16x32_bf16(frag[4 + ks], kf[ks], accB, 0, 0, 0);
        }
        __builtin_amdgcn_s_setprio(0);
        // PReLU(a1) -> H1[buf]
        float v0, v1, v2, v3;
        union { bf16x4 v; uint32_t u[2]; } hh;
        v0 = accA[0]; v1 = accA[1]; v2 = accA[2]; v3 = accA[3];
        v0 = (v0 >= 0.f) ? v0 : alpha * v0;
        v1 = (v1 >= 0.f) ? v1 : alpha * v1;
        v2 = (v2 >= 0.f) ? v2 : alpha * v2;
        v3 = (v3 >= 0.f) ? v3 : alpha * v3;
        hh.u[0] = pk2(v0, v1); hh.u[1] = pk2(v2, v3);
        *(bf16x4*)(&H1[buf][lr * 256 + ((wid * 32 + lg * 4) ^ sw)]) = hh.v;
        v0 = accB[0]; v1 = accB[1]; v2 = accB[2]; v3 = accB[3];
        v0 = (v0 >= 0.f) ? v0 : alpha * v0;
        v1 = (v1 >= 0.f) ? v1 : alpha * v1;
        v2 = (v2 >= 0.f) ? v2 : alpha * v2;
        v3 = (v3 >= 0.f) ? v3 : alpha * v3;
        hh.u[0] = pk2(v0, v1); hh.u[1] = pk2(v2, v3);
        *(bf16x4*)(&H1[buf][lr * 256 + ((wid * 32 + 16 + lg * 4) ^ sw)]) = hh.v;
      }
    } else {
      if (ph >= 1) {                  // GEMM2 on tile ph-1 from H1[buf^1]
#pragma unroll
        for (int r = 0; r < 4; ++r) accA[r] = uv0[r];
        const short* h1b = H1[buf ^ 1];
        __builtin_amdgcn_s_setprio(1);
#pragma unroll
        for (int ks = 0; ks < 8; ++ks) {
          bf16x8 hf = *(const bf16x8*)(&h1b[lr * 256 + ((ks * 32 + lg * 8) ^ sw)]);
          accA = __builtin_amdgcn_mfma_f32_16x16x32_bf16(frag[ks], hf, accA, 0, 0, 0);
        }
        __builtin_amdgcn_s_setprio(0);
        float s = 0.f;
#pragma unroll
        for (int r = 0; r < 4; ++r) {
          float v = accA[r];
          v = (v >= 0.f) ? v : alpha * v;
          s += v * uv1[r];
        }
        s += __shfl_xor(s, 16);
        s += __shfl_xor(s, 32);
        if (lg == 0) wred[wid - 8][(ph - 1) * 16 + lr] = s;
      }
      if (sv) {                        // late LDS write of staged tile
        union { bf16x4 v; uint32_t u[2]; } w;
        w.u[0] = pk2(st.x, st.y); w.u[1] = pk2(st.z, st.w);
        *(bf16x4*)(&Kt[buf ^ 1][srow * 128 + (scol ^ ssw)]) = w.v;
      }
    }
    __syncthreads();
  }

  if (tid < 200) {
    float s = 0.f;
#pragma unroll
    for (int w = 0; w < 8; ++w) s += wred[w][tid];
    scores_g[(size_t)b * 200 + tid] = s;
  }
}

// ---------------- K3: masked softmax + weighted sum (streaming) ----------------
__global__ __launch_bounds__(256) void din_wsum(
    const float* __restrict__ keys, const int* __restrict__ mask,
    const float* __restrict__ scores_g, float* __restrict__ out) {
  __shared__ float wl[208];
  __shared__ float red[8];
  __shared__ float opart[8][128];

  const int tid = threadIdx.x;
  const int b = blockIdx.x;
  const int lane = tid & 63, wid = tid >> 6;  // 4 waves

  float val = NEGV;
  int mk = 0;
  if (tid < 200) {
    mk = mask[(size_t)b * 200 + tid];
    val = mk ? scores_g[(size_t)b * 200 + tid] : NEGV;
  }
  float m = val;
#pragma unroll
  for (int off = 1; off < 64; off <<= 1) m = fmaxf(m, __shfl_xor(m, off));
  if (lane == 0) red[wid] = m;
  __syncthreads();
  float smax = fmaxf(fmaxf(red[0], red[1]), fmaxf(red[2], red[3]));
  float pex = (tid < 200 && mk) ? __expf(val - smax) : 0.f;
  float s = pex;
#pragma unroll
  for (int off = 1; off < 64; off <<= 1) s += __shfl_xor(s, off);
  if (lane == 0) red[4 + wid] = s;
  __syncthreads();
  float ssum = red[4] + red[5] + red[6] + red[7];
  float winv = (ssum > 0.f) ? 1.f / ssum : 0.f;
  if (tid < 208) wl[tid] = (tid < 200) ? pex * winv : 0.f;
  __syncthreads();

  {
    const int d4 = (tid & 31) << 2;  // 0..124
    const int slice = tid >> 5;      // 0..7
    float ax = 0.f, ay = 0.f, az = 0.f, aw = 0.f;
    for (int l = slice; l < 200; l += 8) {
      float wv = wl[l];
      float4 kv = *(const float4*)(keys + ((size_t)b * 200 + l) * 128 + d4);
      ax += wv * kv.x; ay += wv * kv.y; az += wv * kv.z; aw += wv * kv.w;
    }
    *(float4*)(&opart[slice][d4]) = make_float4(ax, ay, az, aw);
  }
  __syncthreads();
  if (tid < 128) {
    float acc = 0.f;
#pragma unroll
    for (int i = 0; i < 8; ++i) acc += opart[i][tid];
    out[(size_t)b * 128 + tid] = acc;
  }
}

extern "C" void kernel_launch(void* const* d_in, const int* in_sizes, int n_in,
                              void* d_out, int out_size, void* d_ws, size_t ws_size,
                              hipStream_t stream) {
  const float* query = (const float*)d_in[0];
  const float* keys  = (const float*)d_in[1];
  const int*   maskp = (const int*)d_in[2];
  const float* W1    = (const float*)d_in[3];
  const float* b1    = (const float*)d_in[4];
  const float* a1    = (const float*)d_in[5];
  const float* W2    = (const float*)d_in[6];
  const float* b2    = (const float*)d_in[7];
  const float* a2    = (const float*)d_in[8];
  const float* W3    = (const float*)d_in[9];
  float* out = (float*)d_out;

  // workspace layout
  float* U        = (float*)d_ws;                        // 2 MiB
  short* Wk       = (short*)((char*)d_ws + 2097152);     // 64 KiB
  short* Wd       = Wk + 32768;                          // 64 KiB
  short* W2b      = Wd + 32768;                          // 64 KiB
  float* scores_g = (float*)((char*)d_ws + 2097152 + 196608);  // 1.6 MiB

  prep_weights<<<384, 256, 0, stream>>>(W1, W2, Wk, Wd, W2b);
  prep_u<<<256, 256, 0, stream>>>(query, W1, b1, U);
  din_scores<<<2048, 1024, 0, stream>>>(query, keys, b2, a1, a2, W3,
                                        U, Wk, Wd, W2b, scores_g);
  din_wsum<<<2048, 256, 0, stream>>>(keys, maskp, scores_g, out);
}

// Round 10
// 167.340 us; speedup vs baseline: 2.6525x; 1.1252x over previous
//
#include <hip/hip_runtime.h>
#include <hip/hip_bf16.h>
#include <cstdint>

#define NEGV (-10000.0f)

typedef short bf16x8 __attribute__((ext_vector_type(8)));
typedef short bf16x4 __attribute__((ext_vector_type(4)));
typedef float f32x4 __attribute__((ext_vector_type(4)));

__device__ __forceinline__ short f2bf(float f) {
  union { float f; uint32_t u; } v; v.f = f;
  uint32_t u = v.u + 0x7fffu + ((v.u >> 16) & 1u);
  return (short)(u >> 16);
}
__device__ __forceinline__ float b2f(short s) {
  union { uint32_t u; float f; } v; v.u = ((uint32_t)(uint16_t)s) << 16;
  return v.f;
}
__device__ __forceinline__ uint32_t pk2(float lo, float hi) {
  union { __hip_bfloat162 h2; uint32_t u; } cv;
  cv.h2.x = __float2bfloat16(lo);
  cv.h2.y = __float2bfloat16(hi);
  return cv.u;
}

// ---------------- P1: weight combine + bf16 casts ----------------
__global__ void prep_weights(const float* __restrict__ W1, const float* __restrict__ W2,
                             short* __restrict__ Wk, short* __restrict__ Wd,
                             short* __restrict__ W2b) {
  int idx = blockIdx.x * 256 + threadIdx.x;
  if (idx < 32768) {
    int h = idx >> 7, d = idx & 127;
    Wk[idx] = f2bf(W1[h * 512 + 128 + d] - W1[h * 512 + 256 + d]);
  } else if (idx < 65536) {
    int i = idx - 32768;
    int h = i >> 7, d = i & 127;
    Wd[i] = f2bf(W1[h * 512 + 384 + d]);
  } else {
    int i = idx - 65536;
    W2b[i] = f2bf(W2[i]);
  }
}

// ---------------- P2: U[b][h] = b1[h] + sum_d (W1[h][d]+W1[h][256+d]) * q[b][d] ----
__global__ void prep_u(const float* __restrict__ query, const float* __restrict__ W1,
                       const float* __restrict__ b1, float* __restrict__ U) {
  __shared__ float q8[8][128];
  int tid = threadIdx.x;
  int b0 = blockIdx.x * 8;
  for (int i = tid; i < 1024; i += 256)
    q8[i >> 7][i & 127] = query[(size_t)(b0 + (i >> 7)) * 128 + (i & 127)];
  __syncthreads();
  int h = tid;
  const float4* w0 = (const float4*)(W1 + (size_t)h * 512);
  const float4* w1 = (const float4*)(W1 + (size_t)h * 512 + 256);
  float acc[8];
  float bb = b1[h];
#pragma unroll
  for (int i = 0; i < 8; ++i) acc[i] = bb;
  for (int d4 = 0; d4 < 32; ++d4) {
    float4 wa = w0[d4], wb = w1[d4];
    float wv0 = wa.x + wb.x, wv1 = wa.y + wb.y, wv2 = wa.z + wb.z, wv3 = wa.w + wb.w;
#pragma unroll
    for (int i = 0; i < 8; ++i) {
      float4 qv = ((const float4*)q8[i])[d4];
      acc[i] += wv0 * qv.x + wv1 * qv.y + wv2 * qv.z + wv3 * qv.w;
    }
  }
#pragma unroll
  for (int i = 0; i < 8; ++i) U[(size_t)(b0 + i) * 256 + h] = acc[i];
}

// ---------------- fused: one 1024-thr block per b ----------------
// Waves 0-7 (G1): GEMM1, 32 h each. Waves 8-15 (G2): GEMM2 (16 g each) + key
// staging (prefetch ring, distance ~2.5 phases). 8 phases of 32 l rows,
// 1 barrier/phase. Keys kept bf16 in Kall -> softmax + weighted sum fused at
// the end (no second kernel, no keys re-read).
__global__ __launch_bounds__(1024) void din_fused(
    const float* __restrict__ query, const float* __restrict__ keys,
    const int* __restrict__ mask,
    const float* __restrict__ b2p, const float* __restrict__ a1p,
    const float* __restrict__ a2p, const float* __restrict__ W3,
    const float* __restrict__ U, const short* __restrict__ Wk,
    const short* __restrict__ Wd, const short* __restrict__ W2b,
    float* __restrict__ out) {
  __shared__ short Kall[224 * 128];   // 57.3 KB bf16 keys, XOR-swizzled, write-once
  __shared__ short H1[2][32 * 256];   // 32 KB h1 tiles [l][h], XOR-swizzled
  __shared__ float wred[8][224];      // 7 KB per-G2-wave score partials
  __shared__ float wl[224];           // scores, then softmax weights
  __shared__ float red[16];
  __shared__ float opart[8][128];

  const int tid = threadIdx.x;
  const int b = blockIdx.x;
  const int lane = tid & 63, wid = tid >> 6;  // 16 waves
  const int lr = lane & 15, lg = lane >> 4;
  const bool isG1 = wid < 8;
  const int sw = (lr & 7) << 3;

  bf16x8 frag[8];
  f32x4 accA, accB;
  float uv0[4], uv1[4];
  float alpha;

  if (isG1) {
    alpha = a1p[0];
    const float* qrow = query + (size_t)b * 128;
#pragma unroll
    for (int nt = 0; nt < 2; ++nt) {
      int h = wid * 32 + nt * 16 + lr;
#pragma unroll
      for (int ks = 0; ks < 4; ++ks) {
        int d0 = ks * 32 + lg * 8;
        bf16x8 wk = *(const bf16x8*)(Wk + h * 128 + d0);
        bf16x8 wd = *(const bf16x8*)(Wd + h * 128 + d0);
        float4 q0 = *(const float4*)(qrow + d0);
        float4 q1 = *(const float4*)(qrow + d0 + 4);
        float qv[8] = {q0.x, q0.y, q0.z, q0.w, q1.x, q1.y, q1.z, q1.w};
        float mv[8];
#pragma unroll
        for (int j = 0; j < 8; ++j) mv[j] = b2f(wk[j]) + b2f(wd[j]) * qv[j];
        union { bf16x8 v; uint32_t u[4]; } mm;
#pragma unroll
        for (int j = 0; j < 4; ++j) mm.u[j] = pk2(mv[2 * j], mv[2 * j + 1]);
        frag[nt * 4 + ks] = mm.v;
      }
    }
#pragma unroll
    for (int r = 0; r < 4; ++r) {
      uv0[r] = U[(size_t)b * 256 + wid * 32 + lg * 4 + r];
      uv1[r] = U[(size_t)b * 256 + wid * 32 + 16 + lg * 4 + r];
    }
  } else {
    alpha = a2p[0];
    int g = (wid - 8) * 16 + lr;
#pragma unroll
    for (int ks = 0; ks < 8; ++ks)
      frag[ks] = *(const bf16x8*)(W2b + g * 256 + ks * 32 + lg * 8);
#pragma unroll
    for (int r = 0; r < 4; ++r) {
      int gg = (wid - 8) * 16 + lg * 4 + r;
      uv0[r] = b2p[gg];
      uv1[r] = W3[gg];
    }
  }

  // staging geometry (G2's 512 threads): 32 rows/tile, 16 thr/row, 8 f32 each
  const int j = tid - 512;
  const int srow = j >> 4;            // 0..31
  const int scol = (j & 15) * 8;      // 0..120
  const int ssw = (srow & 7) << 3;

  float4 sa0, sa1, sb0, sb1;          // 2-deep prefetch ring (tile p+2 / p+3)
  if (!isG1) {
    // tiles 0,1 staged directly (rows 0..63, all valid)
#pragma unroll
    for (int t = 0; t < 2; ++t) {
      int row = t * 32 + srow;
      const float4* kp4 = (const float4*)(keys + ((size_t)b * 200 + row) * 128 + scol);
      float4 x0 = kp4[0], x1 = kp4[1];
      union { bf16x8 v; uint32_t u[4]; } w;
      w.u[0] = pk2(x0.x, x0.y); w.u[1] = pk2(x0.z, x0.w);
      w.u[2] = pk2(x1.x, x1.y); w.u[3] = pk2(x1.z, x1.w);
      *(bf16x8*)(&Kall[row * 128 + (scol ^ ssw)]) = w.v;
    }
    // tile 2 into ring (rows 64..95, valid)
    const float4* kp4 = (const float4*)(keys + ((size_t)b * 200 + 64 + srow) * 128 + scol);
    sa0 = kp4[0]; sa1 = kp4[1];
  }
  __syncthreads();

  // ---- 8 phases: G1 computes tile p (p<7); G2 computes tile p-1 (p>=1) ----
  for (int p = 0; p < 8; ++p) {
    const int buf = p & 1;

    if (isG1) {
      if (p < 7) {
#pragma unroll
        for (int s = 0; s < 2; ++s) {
          const int row = p * 32 + s * 16 + lr;
          bf16x8 kf[4];
#pragma unroll
          for (int ks = 0; ks < 4; ++ks)
            kf[ks] = *(const bf16x8*)(&Kall[row * 128 + ((ks * 32 + lg * 8) ^ sw)]);
#pragma unroll
          for (int r = 0; r < 4; ++r) { accA[r] = uv0[r]; accB[r] = uv1[r]; }
          __builtin_amdgcn_s_setprio(1);
#pragma unroll
          for (int ks = 0; ks < 4; ++ks) {
            accA = __builtin_amdgcn_mfma_f32_16x16x32_bf16(frag[ks], kf[ks], accA, 0, 0, 0);
            accB = __builtin_amdgcn_mfma_f32_16x16x32_bf16(frag[4 + ks], kf[ks], accB, 0, 0, 0);
          }
          __builtin_amdgcn_s_setprio(0);
          float v0, v1, v2, v3;
          union { bf16x4 v; uint32_t u[2]; } hh;
          short* h1row = &H1[buf][(s * 16 + lr) * 256];
          v0 = accA[0]; v1 = accA[1]; v2 = accA[2]; v3 = accA[3];
          v0 = (v0 >= 0.f) ? v0 : alpha * v0;
          v1 = (v1 >= 0.f) ? v1 : alpha * v1;
          v2 = (v2 >= 0.f) ? v2 : alpha * v2;
          v3 = (v3 >= 0.f) ? v3 : alpha * v3;
          hh.u[0] = pk2(v0, v1); hh.u[1] = pk2(v2, v3);
          *(bf16x4*)(&h1row[(wid * 32 + lg * 4) ^ sw]) = hh.v;
          v0 = accB[0]; v1 = accB[1]; v2 = accB[2]; v3 = accB[3];
          v0 = (v0 >= 0.f) ? v0 : alpha * v0;
          v1 = (v1 >= 0.f) ? v1 : alpha * v1;
          v2 = (v2 >= 0.f) ? v2 : alpha * v2;
          v3 = (v3 >= 0.f) ? v3 : alpha * v3;
          hh.u[0] = pk2(v0, v1); hh.u[1] = pk2(v2, v3);
          *(bf16x4*)(&h1row[(wid * 32 + 16 + lg * 4) ^ sw]) = hh.v;
        }
      }
    } else {
      // issue loads for tile p+3 (held until phase p+1's write)
      const bool lv = (p + 3 <= 6);
      if (lv) {
        int gl = (p + 3) * 32 + srow;
        sb0 = sb1 = make_float4(0.f, 0.f, 0.f, 0.f);
        if (gl < 200) {
          const float4* kp4 = (const float4*)(keys + ((size_t)b * 200 + gl) * 128 + scol);
          sb0 = kp4[0]; sb1 = kp4[1];
        }
      }
      if (p >= 1) {                   // GEMM2 on tile p-1
        const short* h1b = H1[buf ^ 1];
#pragma unroll
        for (int s = 0; s < 2; ++s) {
#pragma unroll
          for (int r = 0; r < 4; ++r) accA[r] = uv0[r];
          const short* hr = &h1b[(s * 16 + lr) * 256];
          __builtin_amdgcn_s_setprio(1);
#pragma unroll
          for (int ks = 0; ks < 8; ++ks) {
            bf16x8 hf = *(const bf16x8*)(&hr[(ks * 32 + lg * 8) ^ sw]);
            accA = __builtin_amdgcn_mfma_f32_16x16x32_bf16(frag[ks], hf, accA, 0, 0, 0);
          }
          __builtin_amdgcn_s_setprio(0);
          float sc = 0.f;
#pragma unroll
          for (int r = 0; r < 4; ++r) {
            float v = accA[r];
            v = (v >= 0.f) ? v : alpha * v;
            sc += v * uv1[r];
          }
          sc += __shfl_xor(sc, 16);
          sc += __shfl_xor(sc, 32);
          if (lg == 0) wred[wid - 8][(p - 1) * 32 + s * 16 + lr] = sc;
        }
      }
      // write tile p+2 from ring (loaded at phase p-1)
      if (p + 2 <= 6) {
        int row = (p + 2) * 32 + srow;
        union { bf16x8 v; uint32_t u[4]; } w;
        w.u[0] = pk2(sa0.x, sa0.y); w.u[1] = pk2(sa0.z, sa0.w);
        w.u[2] = pk2(sa1.x, sa1.y); w.u[3] = pk2(sa1.z, sa1.w);
        *(bf16x8*)(&Kall[row * 128 + (scol ^ ssw)]) = w.v;
      }
      if (lv) { sa0 = sb0; sa1 = sb1; }
    }
    __syncthreads();
  }

  // ---- score merge ----
  if (tid < 224) {
    float s = 0.f;
#pragma unroll
    for (int w = 0; w < 8; ++w) s += wred[w][tid];
    wl[tid] = s;
  }
  __syncthreads();

  // ---- masked softmax over l=0..199 ----
  float val = NEGV;
  int mk = 0;
  if (tid < 200) {
    mk = mask[(size_t)b * 200 + tid];
    val = mk ? wl[tid] : NEGV;
  }
  float m = val;
#pragma unroll
  for (int off = 1; off < 64; off <<= 1) m = fmaxf(m, __shfl_xor(m, off));
  if (lane == 0) red[wid] = m;
  __syncthreads();
  float smax = red[0];
#pragma unroll
  for (int i = 1; i < 16; ++i) smax = fmaxf(smax, red[i]);
  float pex = (tid < 200 && mk) ? __expf(val - smax) : 0.f;
  float s = pex;
#pragma unroll
  for (int off = 1; off < 64; off <<= 1) s += __shfl_xor(s, off);
  __syncthreads();  // all reads of red done before rewrite
  if (lane == 0) red[wid] = s;
  __syncthreads();
  float ssum = 0.f;
#pragma unroll
  for (int i = 0; i < 16; ++i) ssum += red[i];
  float winv = (ssum > 0.f) ? 1.f / ssum : 0.f;
  if (tid < 224) wl[tid] = (tid < 200) ? pex * winv : 0.f;
  __syncthreads();

  // ---- weighted sum from LDS bf16 keys ----
  {
    const int d = tid & 127, slice = tid >> 7;  // 8 slices
    float acc = 0.f;
    for (int l = slice; l < 200; l += 8) {
      float wv = wl[l];
      acc += wv * b2f(Kall[l * 128 + (d ^ ((l & 7) << 3))]);
    }
    opart[slice][d] = acc;
  }
  __syncthreads();
  if (tid < 128) {
    float acc = 0.f;
#pragma unroll
    for (int i = 0; i < 8; ++i) acc += opart[i][tid];
    out[(size_t)b * 128 + tid] = acc;
  }
}

extern "C" void kernel_launch(void* const* d_in, const int* in_sizes, int n_in,
                              void* d_out, int out_size, void* d_ws, size_t ws_size,
                              hipStream_t stream) {
  const float* query = (const float*)d_in[0];
  const float* keys  = (const float*)d_in[1];
  const int*   maskp = (const int*)d_in[2];
  const float* W1    = (const float*)d_in[3];
  const float* b1    = (const float*)d_in[4];
  const float* a1    = (const float*)d_in[5];
  const float* W2    = (const float*)d_in[6];
  const float* b2    = (const float*)d_in[7];
  const float* a2    = (const float*)d_in[8];
  const float* W3    = (const float*)d_in[9];
  float* out = (float*)d_out;

  float* U   = (float*)d_ws;                         // 2 MiB
  short* Wk  = (short*)((char*)d_ws + 2097152);      // 64 KiB
  short* Wd  = Wk + 32768;                           // 64 KiB
  short* W2b = Wd + 32768;                           // 64 KiB

  prep_weights<<<384, 256, 0, stream>>>(W1, W2, Wk, Wd, W2b);
  prep_u<<<256, 256, 0, stream>>>(query, W1, b1, U);
  din_fused<<<2048, 1024, 0, stream>>>(query, keys, maskp, b2, a1, a2, W3,
                                       U, Wk, Wd, W2b, out);
}

// Round 11
// 165.912 us; speedup vs baseline: 2.6753x; 1.0086x over previous
//
#include <hip/hip_runtime.h>
#include <hip/hip_bf16.h>
#include <cstdint>

#define NEGV (-10000.0f)

typedef short bf16x8 __attribute__((ext_vector_type(8)));
typedef short bf16x4 __attribute__((ext_vector_type(4)));
typedef float f32x4 __attribute__((ext_vector_type(4)));

__device__ __forceinline__ short f2bf(float f) {
  union { float f; uint32_t u; } v; v.f = f;
  uint32_t u = v.u + 0x7fffu + ((v.u >> 16) & 1u);
  return (short)(u >> 16);
}
__device__ __forceinline__ float b2f(short s) {
  union { uint32_t u; float f; } v; v.u = ((uint32_t)(uint16_t)s) << 16;
  return v.f;
}
__device__ __forceinline__ uint32_t pk2(float lo, float hi) {
  union { __hip_bfloat162 h2; uint32_t u; } cv;
  cv.h2.x = __float2bfloat16(lo);
  cv.h2.y = __float2bfloat16(hi);
  return cv.u;
}

// T4 barrier: LDS-only drain, NO vmcnt(0) — in-flight global prefetches
// (private regs, no cross-wave hazard) survive across the barrier.
// __syncthreads() would drain vmcnt(0) and put a full HBM round-trip on
// every phase's critical path (R10 post-mortem: ~6.8k cy/phase).
__device__ __forceinline__ void bar() {
  __builtin_amdgcn_sched_barrier(0);
  asm volatile("s_waitcnt lgkmcnt(0)" ::: "memory");
  __builtin_amdgcn_s_barrier();
  __builtin_amdgcn_sched_barrier(0);
}

// ---------------- P1: weight combine + bf16 casts ----------------
__global__ void prep_weights(const float* __restrict__ W1, const float* __restrict__ W2,
                             short* __restrict__ Wk, short* __restrict__ Wd,
                             short* __restrict__ W2b) {
  int idx = blockIdx.x * 256 + threadIdx.x;
  if (idx < 32768) {
    int h = idx >> 7, d = idx & 127;
    Wk[idx] = f2bf(W1[h * 512 + 128 + d] - W1[h * 512 + 256 + d]);
  } else if (idx < 65536) {
    int i = idx - 32768;
    int h = i >> 7, d = i & 127;
    Wd[i] = f2bf(W1[h * 512 + 384 + d]);
  } else {
    int i = idx - 65536;
    W2b[i] = f2bf(W2[i]);
  }
}

// ---------------- P2: U[b][h] = b1[h] + sum_d (W1[h][d]+W1[h][256+d]) * q[b][d] ----
__global__ void prep_u(const float* __restrict__ query, const float* __restrict__ W1,
                       const float* __restrict__ b1, float* __restrict__ U) {
  __shared__ float q8[8][128];
  int tid = threadIdx.x;
  int b0 = blockIdx.x * 8;
  for (int i = tid; i < 1024; i += 256)
    q8[i >> 7][i & 127] = query[(size_t)(b0 + (i >> 7)) * 128 + (i & 127)];
  __syncthreads();
  int h = tid;
  const float4* w0 = (const float4*)(W1 + (size_t)h * 512);
  const float4* w1 = (const float4*)(W1 + (size_t)h * 512 + 256);
  float acc[8];
  float bb = b1[h];
#pragma unroll
  for (int i = 0; i < 8; ++i) acc[i] = bb;
  for (int d4 = 0; d4 < 32; ++d4) {
    float4 wa = w0[d4], wb = w1[d4];
    float wv0 = wa.x + wb.x, wv1 = wa.y + wb.y, wv2 = wa.z + wb.z, wv3 = wa.w + wb.w;
#pragma unroll
    for (int i = 0; i < 8; ++i) {
      float4 qv = ((const float4*)q8[i])[d4];
      acc[i] += wv0 * qv.x + wv1 * qv.y + wv2 * qv.z + wv3 * qv.w;
    }
  }
#pragma unroll
  for (int i = 0; i < 8; ++i) U[(size_t)(b0 + i) * 256 + h] = acc[i];
}

// ---------------- fused: one 1024-thr block per b ----------------
// Identical structure to R10 (wave-specialized G1/G2, 8 phases, fused
// softmax+wsum) with ONE change: bar() instead of __syncthreads().
__global__ __launch_bounds__(1024) void din_fused(
    const float* __restrict__ query, const float* __restrict__ keys,
    const int* __restrict__ mask,
    const float* __restrict__ b2p, const float* __restrict__ a1p,
    const float* __restrict__ a2p, const float* __restrict__ W3,
    const float* __restrict__ U, const short* __restrict__ Wk,
    const short* __restrict__ Wd, const short* __restrict__ W2b,
    float* __restrict__ out) {
  __shared__ short Kall[224 * 128];   // 57.3 KB bf16 keys, XOR-swizzled, write-once
  __shared__ short H1[2][32 * 256];   // 32 KB h1 tiles [l][h], XOR-swizzled
  __shared__ float wred[8][224];      // 7 KB per-G2-wave score partials
  __shared__ float wl[224];           // scores, then softmax weights
  __shared__ float red[16];
  __shared__ float opart[8][128];

  const int tid = threadIdx.x;
  const int b = blockIdx.x;
  const int lane = tid & 63, wid = tid >> 6;  // 16 waves
  const int lr = lane & 15, lg = lane >> 4;
  const bool isG1 = wid < 8;
  const int sw = (lr & 7) << 3;

  bf16x8 frag[8];
  f32x4 accA, accB;
  float uv0[4], uv1[4];
  float alpha;

  if (isG1) {
    alpha = a1p[0];
    const float* qrow = query + (size_t)b * 128;
#pragma unroll
    for (int nt = 0; nt < 2; ++nt) {
      int h = wid * 32 + nt * 16 + lr;
#pragma unroll
      for (int ks = 0; ks < 4; ++ks) {
        int d0 = ks * 32 + lg * 8;
        bf16x8 wk = *(const bf16x8*)(Wk + h * 128 + d0);
        bf16x8 wd = *(const bf16x8*)(Wd + h * 128 + d0);
        float4 q0 = *(const float4*)(qrow + d0);
        float4 q1 = *(const float4*)(qrow + d0 + 4);
        float qv[8] = {q0.x, q0.y, q0.z, q0.w, q1.x, q1.y, q1.z, q1.w};
        float mv[8];
#pragma unroll
        for (int j = 0; j < 8; ++j) mv[j] = b2f(wk[j]) + b2f(wd[j]) * qv[j];
        union { bf16x8 v; uint32_t u[4]; } mm;
#pragma unroll
        for (int j = 0; j < 4; ++j) mm.u[j] = pk2(mv[2 * j], mv[2 * j + 1]);
        frag[nt * 4 + ks] = mm.v;
      }
    }
#pragma unroll
    for (int r = 0; r < 4; ++r) {
      uv0[r] = U[(size_t)b * 256 + wid * 32 + lg * 4 + r];
      uv1[r] = U[(size_t)b * 256 + wid * 32 + 16 + lg * 4 + r];
    }
  } else {
    alpha = a2p[0];
    int g = (wid - 8) * 16 + lr;
#pragma unroll
    for (int ks = 0; ks < 8; ++ks)
      frag[ks] = *(const bf16x8*)(W2b + g * 256 + ks * 32 + lg * 8);
#pragma unroll
    for (int r = 0; r < 4; ++r) {
      int gg = (wid - 8) * 16 + lg * 4 + r;
      uv0[r] = b2p[gg];
      uv1[r] = W3[gg];
    }
  }

  // staging geometry (G2's 512 threads): 32 rows/tile, 16 thr/row, 8 f32 each
  const int j = tid - 512;
  const int srow = j >> 4;            // 0..31
  const int scol = (j & 15) * 8;      // 0..120
  const int ssw = (srow & 7) << 3;

  float4 sa0, sa1, sb0, sb1;          // 2-deep prefetch ring
  if (!isG1) {
#pragma unroll
    for (int t = 0; t < 2; ++t) {
      int row = t * 32 + srow;
      const float4* kp4 = (const float4*)(keys + ((size_t)b * 200 + row) * 128 + scol);
      float4 x0 = kp4[0], x1 = kp4[1];
      union { bf16x8 v; uint32_t u[4]; } w;
      w.u[0] = pk2(x0.x, x0.y); w.u[1] = pk2(x0.z, x0.w);
      w.u[2] = pk2(x1.x, x1.y); w.u[3] = pk2(x1.z, x1.w);
      *(bf16x8*)(&Kall[row * 128 + (scol ^ ssw)]) = w.v;
    }
    const float4* kp4 = (const float4*)(keys + ((size_t)b * 200 + 64 + srow) * 128 + scol);
    sa0 = kp4[0]; sa1 = kp4[1];
  }
  bar();

  // ---- 8 phases: G1 computes tile p (p<7); G2 computes tile p-1 (p>=1) ----
  for (int p = 0; p < 8; ++p) {
    const int buf = p & 1;

    if (isG1) {
      if (p < 7) {
#pragma unroll
        for (int s = 0; s < 2; ++s) {
          const int row = p * 32 + s * 16 + lr;
          bf16x8 kf[4];
#pragma unroll
          for (int ks = 0; ks < 4; ++ks)
            kf[ks] = *(const bf16x8*)(&Kall[row * 128 + ((ks * 32 + lg * 8) ^ sw)]);
#pragma unroll
          for (int r = 0; r < 4; ++r) { accA[r] = uv0[r]; accB[r] = uv1[r]; }
          __builtin_amdgcn_s_setprio(1);
#pragma unroll
          for (int ks = 0; ks < 4; ++ks) {
            accA = __builtin_amdgcn_mfma_f32_16x16x32_bf16(frag[ks], kf[ks], accA, 0, 0, 0);
            accB = __builtin_amdgcn_mfma_f32_16x16x32_bf16(frag[4 + ks], kf[ks], accB, 0, 0, 0);
          }
          __builtin_amdgcn_s_setprio(0);
          float v0, v1, v2, v3;
          union { bf16x4 v; uint32_t u[2]; } hh;
          short* h1row = &H1[buf][(s * 16 + lr) * 256];
          v0 = accA[0]; v1 = accA[1]; v2 = accA[2]; v3 = accA[3];
          v0 = (v0 >= 0.f) ? v0 : alpha * v0;
          v1 = (v1 >= 0.f) ? v1 : alpha * v1;
          v2 = (v2 >= 0.f) ? v2 : alpha * v2;
          v3 = (v3 >= 0.f) ? v3 : alpha * v3;
          hh.u[0] = pk2(v0, v1); hh.u[1] = pk2(v2, v3);
          *(bf16x4*)(&h1row[(wid * 32 + lg * 4) ^ sw]) = hh.v;
          v0 = accB[0]; v1 = accB[1]; v2 = accB[2]; v3 = accB[3];
          v0 = (v0 >= 0.f) ? v0 : alpha * v0;
          v1 = (v1 >= 0.f) ? v1 : alpha * v1;
          v2 = (v2 >= 0.f) ? v2 : alpha * v2;
          v3 = (v3 >= 0.f) ? v3 : alpha * v3;
          hh.u[0] = pk2(v0, v1); hh.u[1] = pk2(v2, v3);
          *(bf16x4*)(&h1row[(wid * 32 + 16 + lg * 4) ^ sw]) = hh.v;
        }
      }
    } else {
      // issue loads for tile p+3 (consumed at p+1's LDS write; NOT drained
      // at this phase's barrier thanks to bar())
      const bool lv = (p + 3 <= 6);
      if (lv) {
        int gl = (p + 3) * 32 + srow;
        sb0 = sb1 = make_float4(0.f, 0.f, 0.f, 0.f);
        if (gl < 200) {
          const float4* kp4 = (const float4*)(keys + ((size_t)b * 200 + gl) * 128 + scol);
          sb0 = kp4[0]; sb1 = kp4[1];
        }
      }
      if (p >= 1) {                   // GEMM2 on tile p-1
        const short* h1b = H1[buf ^ 1];
#pragma unroll
        for (int s = 0; s < 2; ++s) {
#pragma unroll
          for (int r = 0; r < 4; ++r) accA[r] = uv0[r];
          const short* hr = &h1b[(s * 16 + lr) * 256];
          __builtin_amdgcn_s_setprio(1);
#pragma unroll
          for (int ks = 0; ks < 8; ++ks) {
            bf16x8 hf = *(const bf16x8*)(&hr[(ks * 32 + lg * 8) ^ sw]);
            accA = __builtin_amdgcn_mfma_f32_16x16x32_bf16(frag[ks], hf, accA, 0, 0, 0);
          }
          __builtin_amdgcn_s_setprio(0);
          float sc = 0.f;
#pragma unroll
          for (int r = 0; r < 4; ++r) {
            float v = accA[r];
            v = (v >= 0.f) ? v : alpha * v;
            sc += v * uv1[r];
          }
          sc += __shfl_xor(sc, 16);
          sc += __shfl_xor(sc, 32);
          if (lg == 0) wred[wid - 8][(p - 1) * 32 + s * 16 + lr] = sc;
        }
      }
      // write tile p+2 from ring (loaded at phase p-1; vmcnt wait lands HERE,
      // ~1 full phase after issue — latency covered)
      if (p + 2 <= 6) {
        int row = (p + 2) * 32 + srow;
        union { bf16x8 v; uint32_t u[4]; } w;
        w.u[0] = pk2(sa0.x, sa0.y); w.u[1] = pk2(sa0.z, sa0.w);
        w.u[2] = pk2(sa1.x, sa1.y); w.u[3] = pk2(sa1.z, sa1.w);
        *(bf16x8*)(&Kall[row * 128 + (scol ^ ssw)]) = w.v;
      }
      if (lv) { sa0 = sb0; sa1 = sb1; }
    }
    bar();
  }

  // ---- score merge ----
  if (tid < 224) {
    float s = 0.f;
#pragma unroll
    for (int w = 0; w < 8; ++w) s += wred[w][tid];
    wl[tid] = s;
  }
  bar();

  // ---- masked softmax over l=0..199 ----
  float val = NEGV;
  int mk = 0;
  if (tid < 200) {
    mk = mask[(size_t)b * 200 + tid];
    val = mk ? wl[tid] : NEGV;
  }
  float m = val;
#pragma unroll
  for (int off = 1; off < 64; off <<= 1) m = fmaxf(m, __shfl_xor(m, off));
  if (lane == 0) red[wid] = m;
  bar();
  float smax = red[0];
#pragma unroll
  for (int i = 1; i < 16; ++i) smax = fmaxf(smax, red[i]);
  float pex = (tid < 200 && mk) ? __expf(val - smax) : 0.f;
  float s = pex;
#pragma unroll
  for (int off = 1; off < 64; off <<= 1) s += __shfl_xor(s, off);
  bar();  // all reads of red done before rewrite
  if (lane == 0) red[wid] = s;
  bar();
  float ssum = 0.f;
#pragma unroll
  for (int i = 0; i < 16; ++i) ssum += red[i];
  float winv = (ssum > 0.f) ? 1.f / ssum : 0.f;
  if (tid < 224) wl[tid] = (tid < 200) ? pex * winv : 0.f;
  bar();

  // ---- weighted sum from LDS bf16 keys ----
  {
    const int d = tid & 127, slice = tid >> 7;  // 8 slices
    float acc = 0.f;
    for (int l = slice; l < 200; l += 8) {
      float wv = wl[l];
      acc += wv * b2f(Kall[l * 128 + (d ^ ((l & 7) << 3))]);
    }
    opart[slice][d] = acc;
  }
  bar();
  if (tid < 128) {
    float acc = 0.f;
#pragma unroll
    for (int i = 0; i < 8; ++i) acc += opart[i][tid];
    out[(size_t)b * 128 + tid] = acc;
  }
}

extern "C" void kernel_launch(void* const* d_in, const int* in_sizes, int n_in,
                              void* d_out, int out_size, void* d_ws, size_t ws_size,
                              hipStream_t stream) {
  const float* query = (const float*)d_in[0];
  const float* keys  = (const float*)d_in[1];
  const int*   maskp = (const int*)d_in[2];
  const float* W1    = (const float*)d_in[3];
  const float* b1    = (const float*)d_in[4];
  const float* a1    = (const float*)d_in[5];
  const float* W2    = (const float*)d_in[6];
  const float* b2    = (const float*)d_in[7];
  const float* a2    = (const float*)d_in[8];
  const float* W3    = (const float*)d_in[9];
  float* out = (float*)d_out;

  float* U   = (float*)d_ws;                         // 2 MiB
  short* Wk  = (short*)((char*)d_ws + 2097152);      // 64 KiB
  short* Wd  = Wk + 32768;                           // 64 KiB
  short* W2b = Wd + 32768;                           // 64 KiB

  prep_weights<<<384, 256, 0, stream>>>(W1, W2, Wk, Wd, W2b);
  prep_u<<<256, 256, 0, stream>>>(query, W1, b1, U);
  din_fused<<<2048, 1024, 0, stream>>>(query, keys, maskp, b2, a1, a2, W3,
                                       U, Wk, Wd, W2b, out);
}